// Round 3
// baseline (1051.769 us; speedup 1.0000x reference)
//
#include <hip/hip_runtime.h>

typedef __bf16 bf16;
typedef __bf16 bf16x8 __attribute__((ext_vector_type(8)));
typedef float f32x4 __attribute__((ext_vector_type(4)));

#define D_   1024
#define S_   1024
#define B_   2
#define NTOK 2048
#define FF_  4096
#define NE   8
#define CAP  5120
#define OUTN 2097152

__device__ __forceinline__ float gelu_f(float x) {
    return 0.5f * x * (1.0f + tanhf(0.7978845608028654f * (x + 0.044715f * x * x * x)));
}

__device__ __forceinline__ void split8(const float* s, bf16x8& hi, bf16x8& lo) {
#pragma unroll
    for (int i = 0; i < 8; i++) {
        float v = s[i];
        bf16 h = (bf16)v;
        hi[i] = h;
        lo[i] = (bf16)(v - (float)h);
    }
}

// ---------------------------------------------------------------------------
// RMSNorm: one block per row of 1024. fp32 out + optional bf16 out.
// ---------------------------------------------------------------------------
__global__ __launch_bounds__(256) void rmsnorm_k(const float* __restrict__ x,
                                                 const float* __restrict__ w,
                                                 float* __restrict__ yf,
                                                 bf16* __restrict__ yb) {
    int row = blockIdx.x;
    int t = threadIdx.x;
    const float* xr = x + (size_t)row * D_;
    float4 v = *(const float4*)(xr + t * 4);
    float ss = v.x * v.x + v.y * v.y + v.z * v.z + v.w * v.w;
    for (int off = 32; off; off >>= 1) ss += __shfl_down(ss, off);
    __shared__ float wsum[4];
    if ((t & 63) == 0) wsum[t >> 6] = ss;
    __syncthreads();
    float tot = wsum[0] + wsum[1] + wsum[2] + wsum[3];
    float rr = rsqrtf(tot * (1.0f / D_) + 1e-6f);
    float4 wv = *(const float4*)(w + t * 4);
    float y[4];
    y[0] = v.x * rr * wv.x; y[1] = v.y * rr * wv.y;
    y[2] = v.z * rr * wv.z; y[3] = v.w * rr * wv.w;
    if (yf) *(float4*)(yf + (size_t)row * D_ + t * 4) = *(float4*)y;
    if (yb) {
        bf16 b4[4];
#pragma unroll
        for (int i = 0; i < 4; i++) b4[i] = (bf16)y[i];
        *(uint2*)(yb + (size_t)row * D_ + t * 4) = *(uint2*)b4;
    }
}

// out = x (residual pre-fill for atomic GEMM epilogues)
__global__ __launch_bounds__(256) void copy_k(const float* __restrict__ x, float* __restrict__ o) {
    size_t i = ((size_t)blockIdx.x * 256 + threadIdx.x) * 4;
    *(float4*)(o + i) = *(const float4*)(x + i);
}

// ---------------------------------------------------------------------------
// Transpose + split-cast fp32 [1024][1024] -> bf16 hi/lo [N][K]. (attn weights)
// ---------------------------------------------------------------------------
__global__ __launch_bounds__(256) void trans_split_k(
    const float* __restrict__ w0, const float* __restrict__ w1p,
    const float* __restrict__ w2p, const float* __restrict__ w3,
    bf16* o0h, bf16* o0l, bf16* o1h, bf16* o1l,
    bf16* o2h, bf16* o2l, bf16* o3h, bf16* o3l) {
    int z = blockIdx.z;
    const float* src = (z == 0) ? w0 : (z == 1) ? w1p : (z == 2) ? w2p : w3;
    bf16* dh = (z == 0) ? o0h : (z == 1) ? o1h : (z == 2) ? o2h : o3h;
    bf16* dl = (z == 0) ? o0l : (z == 1) ? o1l : (z == 2) ? o2l : o3l;
    __shared__ float tl[32][33];
    int c0 = blockIdx.x * 32, r0 = blockIdx.y * 32;
    int tx = threadIdx.x & 31, ty = threadIdx.x >> 5;
#pragma unroll
    for (int i = 0; i < 4; i++) {
        int r = ty + i * 8;
        tl[r][tx] = src[(size_t)(r0 + r) * 1024 + c0 + tx];
    }
    __syncthreads();
#pragma unroll
    for (int i = 0; i < 4; i++) {
        int c = ty + i * 8;
        float v = tl[tx][c];
        bf16 hi = (bf16)v;
        dh[(size_t)(c0 + c) * 1024 + r0 + tx] = hi;
        dl[(size_t)(c0 + c) * 1024 + r0 + tx] = (bf16)(v - (float)hi);
    }
}

// ---------------------------------------------------------------------------
// Transpose + cast fp32 -> bf16: in [z][R][C] -> out [z][C][R]  (MoE weights)
// ---------------------------------------------------------------------------
__global__ __launch_bounds__(256) void transpose_cast_k(const float* __restrict__ in,
                                                        bf16* __restrict__ out,
                                                        int R, int C) {
    __shared__ float tl[32][33];
    size_t base = (size_t)blockIdx.z * R * C;
    const float* src = in + base;
    bf16* dst = out + base;
    int c0 = blockIdx.x * 32, r0 = blockIdx.y * 32;
    int tx = threadIdx.x & 31, tyy = threadIdx.x >> 5;
#pragma unroll
    for (int i = 0; i < 4; i++) {
        int r = tyy + i * 8;
        tl[r][tx] = src[(size_t)(r0 + r) * C + c0 + tx];
    }
    __syncthreads();
#pragma unroll
    for (int i = 0; i < 4; i++) {
        int c = tyy + i * 8;
        dst[(size_t)(c0 + c) * R + r0 + tx] = (bf16)tl[tx][c];
    }
}

// ---------------------------------------------------------------------------
// Split-bf16 dense GEMM, A fp32 (split at stage time), B pre-split bf16 [N][K].
// 128x128 tile, BK=32, split-K; fp32 atomic epilogue.
// ---------------------------------------------------------------------------
#define GLD 40

#define GEMM_SPLITA_BODY(KBASE, KITERS, EPILOGUE)                                     \
    __shared__ bf16 Ash[128 * GLD], Asl[128 * GLD], Bsh[128 * GLD], Bsl[128 * GLD];   \
    int t = threadIdx.x;                                                              \
    int m0 = blockIdx.x * 128, n0 = blockIdx.y * 128;                                 \
    int wv = t >> 6, ln = t & 63, wm = wv >> 1, wn = wv & 1;                          \
    int l15 = ln & 15, qd = ln >> 4;                                                  \
    f32x4 acc[4][4];                                                                  \
    _Pragma("unroll") for (int mt = 0; mt < 4; mt++)                                  \
        _Pragma("unroll") for (int nt = 0; nt < 4; nt++)                              \
            acc[mt][nt] = (f32x4){0.f, 0.f, 0.f, 0.f};                                \
    for (int kk = 0; kk < (KITERS); kk++) {                                           \
        int k0 = (KBASE) + kk * 32;                                                   \
        __syncthreads();                                                              \
        _Pragma("unroll") for (int j = 0; j < 2; j++) {                               \
            int idx = t + j * 256;                                                    \
            int row = idx >> 2, kc = (idx & 3) * 8;                                   \
            float a8[8];                                                              \
            *(float4*)a8 = *(const float4*)(Af + (size_t)(m0 + row) * 1024 + k0 + kc); \
            *(float4*)(a8 + 4) = *(const float4*)(Af + (size_t)(m0 + row) * 1024 + k0 + kc + 4); \
            bf16x8 ahi, alo;                                                          \
            split8(a8, ahi, alo);                                                     \
            *(bf16x8*)&Ash[row * GLD + kc] = ahi;                                     \
            *(bf16x8*)&Asl[row * GLD + kc] = alo;                                     \
            *(uint4*)&Bsh[row * GLD + kc] = *(const uint4*)(Bh + (size_t)(n0 + row) * 1024 + k0 + kc); \
            *(uint4*)&Bsl[row * GLD + kc] = *(const uint4*)(Bl + (size_t)(n0 + row) * 1024 + k0 + kc); \
        }                                                                             \
        __syncthreads();                                                              \
        bf16x8 ah[4], al[4], bh[4], bl[4];                                            \
        _Pragma("unroll") for (int mt = 0; mt < 4; mt++) {                            \
            ah[mt] = *(const bf16x8*)&Ash[(wm * 64 + mt * 16 + l15) * GLD + qd * 8];  \
            al[mt] = *(const bf16x8*)&Asl[(wm * 64 + mt * 16 + l15) * GLD + qd * 8];  \
        }                                                                             \
        _Pragma("unroll") for (int nt = 0; nt < 4; nt++) {                            \
            bh[nt] = *(const bf16x8*)&Bsh[(wn * 64 + nt * 16 + l15) * GLD + qd * 8];  \
            bl[nt] = *(const bf16x8*)&Bsl[(wn * 64 + nt * 16 + l15) * GLD + qd * 8];  \
        }                                                                             \
        _Pragma("unroll") for (int mt = 0; mt < 4; mt++)                              \
            _Pragma("unroll") for (int nt = 0; nt < 4; nt++) {                        \
                acc[mt][nt] = __builtin_amdgcn_mfma_f32_16x16x32_bf16(ah[mt], bh[nt], acc[mt][nt], 0, 0, 0); \
                acc[mt][nt] = __builtin_amdgcn_mfma_f32_16x16x32_bf16(ah[mt], bl[nt], acc[mt][nt], 0, 0, 0); \
                acc[mt][nt] = __builtin_amdgcn_mfma_f32_16x16x32_bf16(al[mt], bh[nt], acc[mt][nt], 0, 0, 0); \
            }                                                                         \
    }                                                                                 \
    _Pragma("unroll") for (int mt = 0; mt < 4; mt++)                                  \
        _Pragma("unroll") for (int nt = 0; nt < 4; nt++) {                            \
            int gn = n0 + wn * 64 + nt * 16 + l15;                                    \
            _Pragma("unroll") for (int r = 0; r < 4; r++) {                           \
                int gm = m0 + wm * 64 + mt * 16 + qd * 4 + r;                         \
                float vv = acc[mt][nt][r];                                            \
                EPILOGUE                                                              \
            }                                                                         \
        }

// QKV: grid (16, 8, 6): z = weight*2 + kchunk; split-K=2 atomic into zeroed fp32.
__global__ __launch_bounds__(256) void gemm_qkv_k(
    const float* __restrict__ Af,
    const bf16* __restrict__ Bqh, const bf16* __restrict__ Bql,
    const bf16* __restrict__ Bkh, const bf16* __restrict__ Bkl,
    const bf16* __restrict__ Bvh, const bf16* __restrict__ Bvl,
    float* Cq, float* Ck, float* Cv) {
    int z = blockIdx.z, zw = z >> 1, kch = z & 1;
    const bf16* Bh = (zw == 0) ? Bqh : (zw == 1) ? Bkh : Bvh;
    const bf16* Bl = (zw == 0) ? Bql : (zw == 1) ? Bkl : Bvl;
    float* C = (zw == 0) ? Cq : (zw == 1) ? Ck : Cv;
    GEMM_SPLITA_BODY(kch * 512, 16, {
        atomicAdd(&C[(size_t)gm * D_ + gn], vv);
    })
}

// WO: grid (16, 8, 4): split-K=4 atomic into out (pre-filled with x).
__global__ __launch_bounds__(256) void gemm_wo_k(
    const float* __restrict__ Af,
    const bf16* __restrict__ Bh, const bf16* __restrict__ Bl,
    float* __restrict__ C) {
    int kch = blockIdx.z;
    GEMM_SPLITA_BODY(kch * 256, 8, {
        atomicAdd(&C[(size_t)gm * D_ + gn], vv);
    })
}

// ---------------------------------------------------------------------------
// Split-bf16 MFMA flash attention, fp32 q/k/v in, fp32 out.
// Block = (qt desc, h, b): 64 q-rows, 4 waves; online softmax in C layout.
// ---------------------------------------------------------------------------
#define AP 72

__global__ __launch_bounds__(256) void attn_mfma_k(
    const float* __restrict__ qf, const float* __restrict__ kf,
    const float* __restrict__ vf, float* __restrict__ ao) {
    int qt = (int)gridDim.x - 1 - (int)blockIdx.x;  // deep tiles first
    int h = blockIdx.y, b = blockIdx.z;
    __shared__ bf16 Ksh[64 * AP], Ksl[64 * AP], VTh[64 * AP], VTl[64 * AP];
    __shared__ bf16 Ph[4][16 * AP], Pl[4][16 * AP];
    int t = threadIdx.x, wv = t >> 6, ln = t & 63, l15 = ln & 15, qd = ln >> 4;

    bf16x8 aqh[2], aql[2];
    {
        size_t qb = ((size_t)(b * S_ + qt * 64 + wv * 16 + l15)) * D_ + h * 64 + qd * 8;
        float q8[8];
        *(float4*)q8 = *(const float4*)(qf + qb);
        *(float4*)(q8 + 4) = *(const float4*)(qf + qb + 4);
        split8(q8, aqh[0], aql[0]);
        *(float4*)q8 = *(const float4*)(qf + qb + 32);
        *(float4*)(q8 + 4) = *(const float4*)(qf + qb + 36);
        split8(q8, aqh[1], aql[1]);
    }
    f32x4 oacc[4];
    float mrow[4], lrow[4];
#pragma unroll
    for (int i = 0; i < 4; i++) {
        oacc[i] = (f32x4){0.f, 0.f, 0.f, 0.f};
        mrow[i] = -1e30f; lrow[i] = 0.0f;
    }

    for (int kt = 0; kt <= qt; kt++) {
        __syncthreads();
#pragma unroll
        for (int j = 0; j < 2; j++) {
            int idx = t + j * 256;
            int row = idx >> 3, ch = (idx & 7) * 8;
            size_t g = ((size_t)(b * S_ + kt * 64 + row)) * D_ + h * 64 + ch;
            float k8[8], v8[8];
            *(float4*)k8 = *(const float4*)(kf + g);
            *(float4*)(k8 + 4) = *(const float4*)(kf + g + 4);
            *(float4*)v8 = *(const float4*)(vf + g);
            *(float4*)(v8 + 4) = *(const float4*)(vf + g + 4);
            bf16x8 khi, klo, vhi, vlo;
            split8(k8, khi, klo);
            split8(v8, vhi, vlo);
            *(bf16x8*)&Ksh[row * AP + ch] = khi;
            *(bf16x8*)&Ksl[row * AP + ch] = klo;
#pragma unroll
            for (int jj = 0; jj < 8; jj++) {
                VTh[(ch + jj) * AP + row] = vhi[jj];
                VTl[(ch + jj) * AP + row] = vlo[jj];
            }
        }
        __syncthreads();

        f32x4 sacc[4];
#pragma unroll
        for (int nt = 0; nt < 4; nt++) sacc[nt] = (f32x4){0.f, 0.f, 0.f, 0.f};
#pragma unroll
        for (int ks = 0; ks < 2; ks++) {
#pragma unroll
            for (int nt = 0; nt < 4; nt++) {
                bf16x8 bh = *(const bf16x8*)&Ksh[(nt * 16 + l15) * AP + ks * 32 + qd * 8];
                bf16x8 bl = *(const bf16x8*)&Ksl[(nt * 16 + l15) * AP + ks * 32 + qd * 8];
                sacc[nt] = __builtin_amdgcn_mfma_f32_16x16x32_bf16(aqh[ks], bh, sacc[nt], 0, 0, 0);
                sacc[nt] = __builtin_amdgcn_mfma_f32_16x16x32_bf16(aqh[ks], bl, sacc[nt], 0, 0, 0);
                sacc[nt] = __builtin_amdgcn_mfma_f32_16x16x32_bf16(aql[ks], bh, sacc[nt], 0, 0, 0);
            }
        }
        bool diag = (kt == qt);
#pragma unroll
        for (int r = 0; r < 4; r++) {
            float s0[4];
#pragma unroll
            for (int nt = 0; nt < 4; nt++) {
                s0[nt] = sacc[nt][r] * 0.125f;
                if (diag && (nt * 16 + l15) > (wv * 16 + qd * 4 + r)) s0[nt] = -1e30f;
            }
            float vmax = fmaxf(fmaxf(s0[0], s0[1]), fmaxf(s0[2], s0[3]));
            for (int off = 1; off < 16; off <<= 1) vmax = fmaxf(vmax, __shfl_xor(vmax, off));
            float mnew = fmaxf(mrow[r], vmax);
            float alpha = expf(mrow[r] - mnew);
            float p[4], rs = 0.0f;
#pragma unroll
            for (int nt = 0; nt < 4; nt++) { p[nt] = expf(s0[nt] - mnew); rs += p[nt]; }
            for (int off = 1; off < 16; off <<= 1) rs += __shfl_xor(rs, off);
            lrow[r] = lrow[r] * alpha + rs;
            mrow[r] = mnew;
#pragma unroll
            for (int nt = 0; nt < 4; nt++) oacc[nt][r] *= alpha;
            int prow = qd * 4 + r;
#pragma unroll
            for (int nt = 0; nt < 4; nt++) {
                bf16 hi = (bf16)p[nt];
                Ph[wv][prow * AP + nt * 16 + l15] = hi;
                Pl[wv][prow * AP + nt * 16 + l15] = (bf16)(p[nt] - (float)hi);
            }
        }
        // PV: same-wave LDS RAW (in-order DS pipe), no barrier needed.
#pragma unroll
        for (int ks2 = 0; ks2 < 2; ks2++) {
            bf16x8 aph = *(const bf16x8*)&Ph[wv][l15 * AP + ks2 * 32 + qd * 8];
            bf16x8 apl = *(const bf16x8*)&Pl[wv][l15 * AP + ks2 * 32 + qd * 8];
#pragma unroll
            for (int nt = 0; nt < 4; nt++) {
                bf16x8 bvh = *(const bf16x8*)&VTh[(nt * 16 + l15) * AP + ks2 * 32 + qd * 8];
                bf16x8 bvl = *(const bf16x8*)&VTl[(nt * 16 + l15) * AP + ks2 * 32 + qd * 8];
                oacc[nt] = __builtin_amdgcn_mfma_f32_16x16x32_bf16(aph, bvh, oacc[nt], 0, 0, 0);
                oacc[nt] = __builtin_amdgcn_mfma_f32_16x16x32_bf16(aph, bvl, oacc[nt], 0, 0, 0);
                oacc[nt] = __builtin_amdgcn_mfma_f32_16x16x32_bf16(apl, bvh, oacc[nt], 0, 0, 0);
            }
        }
    }

#pragma unroll
    for (int r = 0; r < 4; r++) {
        float inv = 1.0f / lrow[r];
        size_t rowa = ((size_t)(b * S_ + qt * 64 + wv * 16 + qd * 4 + r)) * D_ + h * 64;
#pragma unroll
        for (int nt = 0; nt < 4; nt++) {
            ao[rowa + nt * 16 + l15] = oacc[nt][r] * inv;
        }
    }
}

// ---------------------------------------------------------------------------
// Router: 4 tokens/block (wave each). fp32 logits -> softmax -> top2.
// ---------------------------------------------------------------------------
__global__ __launch_bounds__(256) void router_k(const float* __restrict__ h,
                                                const float* __restrict__ rw,
                                                int* __restrict__ tidx,
                                                float* __restrict__ tgate,
                                                int* __restrict__ ecnt,
                                                float* __restrict__ psum) {
    int wv = threadIdx.x >> 6, ln = threadIdx.x & 63;
    int tok = blockIdx.x * 4 + wv;
    const float* hr = h + (size_t)tok * D_;
    float acc[NE];
#pragma unroll
    for (int e = 0; e < NE; e++) acc[e] = 0.0f;
    int base = ln * 16;
#pragma unroll
    for (int c = 0; c < 4; c++) {
        float4 hv = *(const float4*)(hr + base + c * 4);
        const float* rp = rw + (size_t)(base + c * 4) * NE;
        float hx[4] = {hv.x, hv.y, hv.z, hv.w};
#pragma unroll
        for (int jj = 0; jj < 4; jj++)
#pragma unroll
            for (int e = 0; e < NE; e++)
                acc[e] = fmaf(hx[jj], rp[jj * NE + e], acc[e]);
    }
#pragma unroll
    for (int e = 0; e < NE; e++)
        for (int off = 32; off; off >>= 1) acc[e] += __shfl_down(acc[e], off);

    __shared__ float pb[4][NE];
    if (ln == 0) {
        float mx = acc[0];
#pragma unroll
        for (int e = 1; e < NE; e++) mx = fmaxf(mx, acc[e]);
        float p[NE], ssum = 0.0f;
#pragma unroll
        for (int e = 0; e < NE; e++) { p[e] = expf(acc[e] - mx); ssum += p[e]; }
        float inv = 1.0f / ssum;
#pragma unroll
        for (int e = 0; e < NE; e++) p[e] *= inv;
        int i0 = 0; float b0 = p[0];
#pragma unroll
        for (int e = 1; e < NE; e++) if (p[e] > b0) { b0 = p[e]; i0 = e; }
        int i1 = -1; float b1v = -1.0f;
#pragma unroll
        for (int e = 0; e < NE; e++) if (e != i0 && p[e] > b1v) { b1v = p[e]; i1 = e; }
        tidx[tok * 2] = i0; tidx[tok * 2 + 1] = i1;
        tgate[tok * 2] = b0; tgate[tok * 2 + 1] = b1v;
        atomicAdd(&ecnt[i0], 1);
        atomicAdd(&ecnt[i1], 1);
#pragma unroll
        for (int e = 0; e < NE; e++) pb[wv][e] = p[e];
    }
    __syncthreads();
    if (threadIdx.x < NE) {
        float s2 = pb[0][threadIdx.x] + pb[1][threadIdx.x] + pb[2][threadIdx.x] + pb[3][threadIdx.x];
        atomicAdd(&psum[threadIdx.x], s2);
    }
}

__global__ void passb_k(const int* __restrict__ ecnt, const float* __restrict__ psum,
                        int* __restrict__ eoffp, int* __restrict__ ecnt2,
                        float* __restrict__ out_tail) {
    if (threadIdx.x == 0) {
        int off = 0; float loss = 0.0f;
        for (int e = 0; e < NE; e++) {
            eoffp[e] = off;
            int c = ecnt[e];
            off += (c + 127) & ~127;
            loss += (c * (1.0f / 4096.0f)) * (psum[e] * (1.0f / 2048.0f));
            out_tail[1 + e] = (float)c;
            ecnt2[e] = 0;
        }
        eoffp[NE] = off;
        out_tail[0] = 8.0f * loss;
    }
}

__global__ __launch_bounds__(256) void scatter_k(const int* __restrict__ tidx,
                                                 const float* __restrict__ tgate,
                                                 const int* __restrict__ eoffp,
                                                 int* __restrict__ ecnt2,
                                                 int* __restrict__ stok,
                                                 float* __restrict__ sgate) {
    int tok = blockIdx.x * 256 + threadIdx.x;
    for (int k = 0; k < 2; k++) {
        int e = tidx[tok * 2 + k];
        int pos = eoffp[e] + atomicAdd(&ecnt2[e], 1);
        stok[pos] = tok;
        sgate[pos] = tgate[tok * 2 + k];
    }
}

// ---------------------------------------------------------------------------
// MoE MFMA GEMMs (plain bf16): 128x128 tile, BK=32, 4 waves 2x2.
// ---------------------------------------------------------------------------
#define MLD 40

__global__ __launch_bounds__(256) void moe_gemm1_k(const bf16* __restrict__ hB,
                                                   const bf16* __restrict__ w1t,
                                                   const float* __restrict__ b1,
                                                   const int* __restrict__ eoffp,
                                                   const int* __restrict__ stok,
                                                   bf16* __restrict__ act) {
    int m0 = blockIdx.x * 128, n0 = blockIdx.y * 128;
    if (m0 >= eoffp[NE]) return;
    int e = 0;
#pragma unroll
    for (int i = 1; i < NE; i++) if (m0 >= eoffp[i]) e = i;

    __shared__ bf16 As[128 * MLD];
    __shared__ bf16 Bs[128 * MLD];
    __shared__ int tok_l[128];
    int t = threadIdx.x;
    if (t < 128) tok_l[t] = stok[m0 + t];

    int wv = t >> 6, ln = t & 63;
    int wm = wv >> 1, wn = wv & 1;
    int lane15 = ln & 15, quad = ln >> 4;
    f32x4 acc[4][4];
#pragma unroll
    for (int mt = 0; mt < 4; mt++)
#pragma unroll
        for (int nt = 0; nt < 4; nt++) acc[mt][nt] = (f32x4){0.f, 0.f, 0.f, 0.f};

    const bf16* Bbase = w1t + ((size_t)e * FF_ + n0) * D_;

    for (int k0 = 0; k0 < D_; k0 += 32) {
        __syncthreads();
#pragma unroll
        for (int j = 0; j < 2; j++) {
            int idx = t + j * 256;
            int row = idx >> 2, kc = (idx & 3) * 8;
            uint4 av = *(const uint4*)(hB + (size_t)tok_l[row] * D_ + k0 + kc);
            *(uint4*)&As[row * MLD + kc] = av;
            uint4 bv = *(const uint4*)(Bbase + (size_t)row * D_ + k0 + kc);
            *(uint4*)&Bs[row * MLD + kc] = bv;
        }
        __syncthreads();
        bf16x8 af[4], bfr[4];
#pragma unroll
        for (int mt = 0; mt < 4; mt++)
            af[mt] = *(const bf16x8*)&As[(wm * 64 + mt * 16 + lane15) * MLD + quad * 8];
#pragma unroll
        for (int nt = 0; nt < 4; nt++)
            bfr[nt] = *(const bf16x8*)&Bs[(wn * 64 + nt * 16 + lane15) * MLD + quad * 8];
#pragma unroll
        for (int mt = 0; mt < 4; mt++)
#pragma unroll
            for (int nt = 0; nt < 4; nt++)
                acc[mt][nt] = __builtin_amdgcn_mfma_f32_16x16x32_bf16(af[mt], bfr[nt], acc[mt][nt], 0, 0, 0);
    }

    const float* b1e = b1 + (size_t)e * FF_;
#pragma unroll
    for (int mt = 0; mt < 4; mt++)
#pragma unroll
        for (int nt = 0; nt < 4; nt++) {
            int gn = n0 + wn * 64 + nt * 16 + lane15;
            float bias = b1e[gn];
#pragma unroll
            for (int r = 0; r < 4; r++) {
                int gm = m0 + wm * 64 + mt * 16 + quad * 4 + r;
                float vv = acc[mt][nt][r] + bias;
                act[(size_t)gm * FF_ + gn] = (bf16)gelu_f(vv);
            }
        }
}

// split-K=4: grid (CAP/128, D/128, 4); bias added by kchunk 0 only.
__global__ __launch_bounds__(256) void moe_gemm2_k(const bf16* __restrict__ act,
                                                   const bf16* __restrict__ w2t,
                                                   const float* __restrict__ b2,
                                                   const int* __restrict__ eoffp,
                                                   const int* __restrict__ stok,
                                                   const float* __restrict__ sgate,
                                                   float* __restrict__ out) {
    int m0 = blockIdx.x * 128, n0 = blockIdx.y * 128;
    if (m0 >= eoffp[NE]) return;
    int kch = blockIdx.z;
    int e = 0;
#pragma unroll
    for (int i = 1; i < NE; i++) if (m0 >= eoffp[i]) e = i;

    __shared__ bf16 As[128 * MLD];
    __shared__ bf16 Bs[128 * MLD];
    __shared__ int tok_l[128];
    __shared__ float gate_l[128];
    int t = threadIdx.x;
    if (t < 128) { tok_l[t] = stok[m0 + t]; gate_l[t] = sgate[m0 + t]; }

    int wv = t >> 6, ln = t & 63;
    int wm = wv >> 1, wn = wv & 1;
    int lane15 = ln & 15, quad = ln >> 4;
    f32x4 acc[4][4];
#pragma unroll
    for (int mt = 0; mt < 4; mt++)
#pragma unroll
        for (int nt = 0; nt < 4; nt++) acc[mt][nt] = (f32x4){0.f, 0.f, 0.f, 0.f};

    const bf16* Bbase = w2t + ((size_t)e * D_ + n0) * FF_;

    int kbase = kch * 1024;
    for (int kk = 0; kk < 32; kk++) {
        int k0 = kbase + kk * 32;
        __syncthreads();
#pragma unroll
        for (int j = 0; j < 2; j++) {
            int idx = t + j * 256;
            int row = idx >> 2, kc = (idx & 3) * 8;
            uint4 av = *(const uint4*)(act + (size_t)(m0 + row) * FF_ + k0 + kc);
            *(uint4*)&As[row * MLD + kc] = av;
            uint4 bv = *(const uint4*)(Bbase + (size_t)row * FF_ + k0 + kc);
            *(uint4*)&Bs[row * MLD + kc] = bv;
        }
        __syncthreads();
        bf16x8 af[4], bfr[4];
#pragma unroll
        for (int mt = 0; mt < 4; mt++)
            af[mt] = *(const bf16x8*)&As[(wm * 64 + mt * 16 + lane15) * MLD + quad * 8];
#pragma unroll
        for (int nt = 0; nt < 4; nt++)
            bfr[nt] = *(const bf16x8*)&Bs[(wn * 64 + nt * 16 + lane15) * MLD + quad * 8];
#pragma unroll
        for (int mt = 0; mt < 4; mt++)
#pragma unroll
            for (int nt = 0; nt < 4; nt++)
                acc[mt][nt] = __builtin_amdgcn_mfma_f32_16x16x32_bf16(af[mt], bfr[nt], acc[mt][nt], 0, 0, 0);
    }

    const float* b2e = b2 + (size_t)e * D_;
#pragma unroll
    for (int mt = 0; mt < 4; mt++)
#pragma unroll
        for (int nt = 0; nt < 4; nt++) {
            int gn = n0 + wn * 64 + nt * 16 + lane15;
            float bias = (kch == 0) ? b2e[gn] : 0.0f;
#pragma unroll
            for (int r = 0; r < 4; r++) {
                int lm = wm * 64 + mt * 16 + quad * 4 + r;
                int tok = tok_l[lm];
                float g = gate_l[lm];
                atomicAdd(out + (size_t)tok * D_ + gn, g * (acc[mt][nt][r] + bias));
            }
        }
}

// ---------------------------------------------------------------------------
extern "C" void kernel_launch(void* const* d_in, const int* in_sizes, int n_in,
                              void* d_out, int out_size, void* d_ws, size_t ws_size,
                              hipStream_t stream) {
    const float* x   = (const float*)d_in[0];
    const float* anw = (const float*)d_in[1];
    const float* wq  = (const float*)d_in[2];
    const float* wk  = (const float*)d_in[3];
    const float* wv  = (const float*)d_in[4];
    const float* wo  = (const float*)d_in[5];
    const float* mnw = (const float*)d_in[6];
    const float* rw  = (const float*)d_in[7];
    const float* w1  = (const float*)d_in[8];
    const float* b1  = (const float*)d_in[9];
    const float* w2  = (const float*)d_in[10];
    const float* b2  = (const float*)d_in[11];
    float* out = (float*)d_out;

    char* p = (char*)d_ws;
    auto take = [&](size_t n) { char* r = p; p += (n + 255) & ~(size_t)255; return r; };
    float* h1_f = (float*)take((size_t)OUTN * 4);   // later aliased as ao_f
    float* q_f  = (float*)take((size_t)OUTN * 4);   // later aliased as h_f
    float* k_f  = (float*)take((size_t)OUTN * 4);   // later aliased as h_b
    float* v_f  = (float*)take((size_t)OUTN * 4);
    bf16* wqth = (bf16*)take((size_t)D_ * D_ * 2);
    bf16* wqtl = (bf16*)take((size_t)D_ * D_ * 2);
    bf16* wkth = (bf16*)take((size_t)D_ * D_ * 2);
    bf16* wktl = (bf16*)take((size_t)D_ * D_ * 2);
    bf16* wvth = (bf16*)take((size_t)D_ * D_ * 2);
    bf16* wvtl = (bf16*)take((size_t)D_ * D_ * 2);
    bf16* woth = (bf16*)take((size_t)D_ * D_ * 2);
    bf16* wotl = (bf16*)take((size_t)D_ * D_ * 2);
    bf16* w1t = (bf16*)take((size_t)NE * FF_ * D_ * 2);
    bf16* w2t = (bf16*)take((size_t)NE * FF_ * D_ * 2);
    bf16* act = (bf16*)take((size_t)CAP * FF_ * 2);
    int*   tidx  = (int*)take(NTOK * 2 * 4);
    float* tgate = (float*)take(NTOK * 2 * 4);
    int*   ecnt  = (int*)take(64);
    int*   ecnt2 = (int*)take(64);
    float* psum  = (float*)take(64);
    int*   eoffp = (int*)take(64);
    int*   stok  = (int*)take(CAP * 4);
    float* sgate = (float*)take(CAP * 4);

    // aliases over dead buffers
    float* ao_f = h1_f;          // h1 dead after QKV gemm
    float* h_f  = q_f;           // q dead after attention
    bf16*  h_b  = (bf16*)k_f;    // k dead after attention

    hipMemsetAsync(ecnt, 0, NE * 4, stream);
    hipMemsetAsync(psum, 0, NE * 4, stream);
    hipMemsetAsync(stok, 0, CAP * 4, stream);
    hipMemsetAsync(sgate, 0, CAP * 4, stream);
    hipMemsetAsync(q_f, 0, (size_t)OUTN * 4, stream);
    hipMemsetAsync(k_f, 0, (size_t)OUTN * 4, stream);
    hipMemsetAsync(v_f, 0, (size_t)OUTN * 4, stream);

    // weight transposes
    trans_split_k<<<dim3(32, 32, 4), 256, 0, stream>>>(wq, wk, wv, wo,
        wqth, wqtl, wkth, wktl, wvth, wvtl, woth, wotl);
    transpose_cast_k<<<dim3(FF_ / 32, D_ / 32, NE), 256, 0, stream>>>(w1, w1t, D_, FF_);
    transpose_cast_k<<<dim3(D_ / 32, FF_ / 32, NE), 256, 0, stream>>>(w2, w2t, FF_, D_);

    // attention path
    rmsnorm_k<<<NTOK, 256, 0, stream>>>(x, anw, h1_f, nullptr);
    gemm_qkv_k<<<dim3(16, 8, 6), 256, 0, stream>>>(h1_f,
        wqth, wqtl, wkth, wktl, wvth, wvtl, q_f, k_f, v_f);
    attn_mfma_k<<<dim3(16, 16, 2), 256, 0, stream>>>(q_f, k_f, v_f, ao_f);
    copy_k<<<OUTN / 1024, 256, 0, stream>>>(x, out);                 // out = x
    gemm_wo_k<<<dim3(16, 8, 4), 256, 0, stream>>>(ao_f, woth, wotl, out);  // out += ao@wo

    // MoE
    rmsnorm_k<<<NTOK, 256, 0, stream>>>(out, mnw, h_f, h_b);
    router_k<<<NTOK / 4, 256, 0, stream>>>(h_f, rw, tidx, tgate, ecnt, psum);
    passb_k<<<1, 64, 0, stream>>>(ecnt, psum, eoffp, ecnt2, out + OUTN);
    scatter_k<<<NTOK / 256, 256, 0, stream>>>(tidx, tgate, eoffp, ecnt2, stok, sgate);
    moe_gemm1_k<<<dim3(CAP / 128, FF_ / 128), 256, 0, stream>>>(h_b, w1t, b1, eoffp, stok, act);
    moe_gemm2_k<<<dim3(CAP / 128, D_ / 128, 4), 256, 0, stream>>>(act, w2t, b2, eoffp, stok, sgate, out);
}

// Round 4
// 842.123 us; speedup vs baseline: 1.2489x; 1.2489x over previous
//
#include <hip/hip_runtime.h>

typedef __bf16 bf16;
typedef __bf16 bf16x8 __attribute__((ext_vector_type(8)));
typedef float f32x4 __attribute__((ext_vector_type(4)));

#define D_   1024
#define S_   1024
#define B_   2
#define NTOK 2048
#define FF_  4096
#define NE   8
#define CAP  5120
#define OUTN 2097152

__device__ __forceinline__ float gelu_f(float x) {
    return 0.5f * x * (1.0f + tanhf(0.7978845608028654f * (x + 0.044715f * x * x * x)));
}

// ---------------------------------------------------------------------------
// RMSNorm: one block per row of 1024. Optional fp32 / bf16-hi / bf16-lo outs.
// ---------------------------------------------------------------------------
__global__ __launch_bounds__(256) void rmsnorm_k(const float* __restrict__ x,
                                                 const float* __restrict__ w,
                                                 float* __restrict__ yf,
                                                 bf16* __restrict__ yhi,
                                                 bf16* __restrict__ ylo) {
    int row = blockIdx.x;
    int t = threadIdx.x;
    const float* xr = x + (size_t)row * D_;
    float4 v = *(const float4*)(xr + t * 4);
    float ss = v.x * v.x + v.y * v.y + v.z * v.z + v.w * v.w;
    for (int off = 32; off; off >>= 1) ss += __shfl_down(ss, off);
    __shared__ float wsum[4];
    if ((t & 63) == 0) wsum[t >> 6] = ss;
    __syncthreads();
    float tot = wsum[0] + wsum[1] + wsum[2] + wsum[3];
    float rr = rsqrtf(tot * (1.0f / D_) + 1e-6f);
    float4 wv = *(const float4*)(w + t * 4);
    float y[4];
    y[0] = v.x * rr * wv.x; y[1] = v.y * rr * wv.y;
    y[2] = v.z * rr * wv.z; y[3] = v.w * rr * wv.w;
    if (yf) *(float4*)(yf + (size_t)row * D_ + t * 4) = *(float4*)y;
    if (yhi) {
#pragma unroll
        for (int i = 0; i < 4; i++) {
            bf16 hi = (bf16)y[i];
            yhi[(size_t)row * D_ + t * 4 + i] = hi;
            if (ylo) ylo[(size_t)row * D_ + t * 4 + i] = (bf16)(y[i] - (float)hi);
        }
    }
}

// ---------------------------------------------------------------------------
// Transpose + split-cast fp32 [1024][1024] -> bf16 hi/lo [N][K]. (attn weights)
// ---------------------------------------------------------------------------
__global__ __launch_bounds__(256) void trans_split_k(
    const float* __restrict__ w0, const float* __restrict__ w1p,
    const float* __restrict__ w2p, const float* __restrict__ w3,
    bf16* o0h, bf16* o0l, bf16* o1h, bf16* o1l,
    bf16* o2h, bf16* o2l, bf16* o3h, bf16* o3l) {
    int z = blockIdx.z;
    const float* src = (z == 0) ? w0 : (z == 1) ? w1p : (z == 2) ? w2p : w3;
    bf16* dh = (z == 0) ? o0h : (z == 1) ? o1h : (z == 2) ? o2h : o3h;
    bf16* dl = (z == 0) ? o0l : (z == 1) ? o1l : (z == 2) ? o2l : o3l;
    __shared__ float tl[32][33];
    int c0 = blockIdx.x * 32, r0 = blockIdx.y * 32;
    int tx = threadIdx.x & 31, ty = threadIdx.x >> 5;
#pragma unroll
    for (int i = 0; i < 4; i++) {
        int r = ty + i * 8;
        tl[r][tx] = src[(size_t)(r0 + r) * 1024 + c0 + tx];
    }
    __syncthreads();
#pragma unroll
    for (int i = 0; i < 4; i++) {
        int c = ty + i * 8;
        float v = tl[tx][c];
        bf16 hi = (bf16)v;
        dh[(size_t)(c0 + c) * 1024 + r0 + tx] = hi;
        dl[(size_t)(c0 + c) * 1024 + r0 + tx] = (bf16)(v - (float)hi);
    }
}

// ---------------------------------------------------------------------------
// Transpose + cast fp32 -> bf16: in [z][R][C] -> out [z][C][R]  (MoE weights)
// ---------------------------------------------------------------------------
__global__ __launch_bounds__(256) void transpose_cast_k(const float* __restrict__ in,
                                                        bf16* __restrict__ out,
                                                        int R, int C) {
    __shared__ float tl[32][33];
    size_t base = (size_t)blockIdx.z * R * C;
    const float* src = in + base;
    bf16* dst = out + base;
    int c0 = blockIdx.x * 32, r0 = blockIdx.y * 32;
    int tx = threadIdx.x & 31, tyy = threadIdx.x >> 5;
#pragma unroll
    for (int i = 0; i < 4; i++) {
        int r = tyy + i * 8;
        tl[r][tx] = src[(size_t)(r0 + r) * C + c0 + tx];
    }
    __syncthreads();
#pragma unroll
    for (int i = 0; i < 4; i++) {
        int c = tyy + i * 8;
        dst[(size_t)(c0 + c) * R + r0 + tx] = (bf16)tl[tx][c];
    }
}

// ---------------------------------------------------------------------------
// Split-bf16 dense GEMM, 64x64 tile, BK=32, 4 waves (each owns 16-wide n-strip),
// K=1024. A hi/lo [M][K], B hi/lo [N][K]. 3-product Markidis MFMA.
// ---------------------------------------------------------------------------
#define GLD 40

#define GEMM64_SPLIT_BODY(N0EXPR, EPILOGUE)                                            \
    __shared__ bf16 Ash[64 * GLD], Asl[64 * GLD], Bsh[64 * GLD], Bsl[64 * GLD];        \
    int t = threadIdx.x;                                                               \
    int m0 = blockIdx.x * 64;                                                          \
    int n0 = (N0EXPR);                                                                 \
    int wv = t >> 6, ln = t & 63, l15 = ln & 15, qd = ln >> 4;                         \
    int srow = t >> 2, skc = (t & 3) * 8;                                              \
    f32x4 acc[4];                                                                      \
    _Pragma("unroll") for (int mt = 0; mt < 4; mt++) acc[mt] = (f32x4){0.f,0.f,0.f,0.f}; \
    for (int k0 = 0; k0 < 1024; k0 += 32) {                                            \
        __syncthreads();                                                               \
        *(bf16x8*)&Ash[srow * GLD + skc] = *(const bf16x8*)(Ah + (size_t)(m0 + srow) * 1024 + k0 + skc); \
        *(bf16x8*)&Asl[srow * GLD + skc] = *(const bf16x8*)(Al + (size_t)(m0 + srow) * 1024 + k0 + skc); \
        *(bf16x8*)&Bsh[srow * GLD + skc] = *(const bf16x8*)(Bh + (size_t)(n0 + srow) * 1024 + k0 + skc); \
        *(bf16x8*)&Bsl[srow * GLD + skc] = *(const bf16x8*)(Bl + (size_t)(n0 + srow) * 1024 + k0 + skc); \
        __syncthreads();                                                               \
        bf16x8 ah[4], al[4];                                                           \
        _Pragma("unroll") for (int mt = 0; mt < 4; mt++) {                             \
            ah[mt] = *(const bf16x8*)&Ash[(mt * 16 + l15) * GLD + qd * 8];             \
            al[mt] = *(const bf16x8*)&Asl[(mt * 16 + l15) * GLD + qd * 8];             \
        }                                                                              \
        bf16x8 bh = *(const bf16x8*)&Bsh[(wv * 16 + l15) * GLD + qd * 8];              \
        bf16x8 bl = *(const bf16x8*)&Bsl[(wv * 16 + l15) * GLD + qd * 8];              \
        _Pragma("unroll") for (int mt = 0; mt < 4; mt++) {                             \
            acc[mt] = __builtin_amdgcn_mfma_f32_16x16x32_bf16(ah[mt], bh, acc[mt], 0, 0, 0); \
            acc[mt] = __builtin_amdgcn_mfma_f32_16x16x32_bf16(ah[mt], bl, acc[mt], 0, 0, 0); \
            acc[mt] = __builtin_amdgcn_mfma_f32_16x16x32_bf16(al[mt], bh, acc[mt], 0, 0, 0); \
        }                                                                              \
    }                                                                                  \
    int gnl = wv * 16 + l15;                                                           \
    _Pragma("unroll") for (int mt = 0; mt < 4; mt++)                                   \
        _Pragma("unroll") for (int r = 0; r < 4; r++) {                                \
            int gm = m0 + mt * 16 + qd * 4 + r;                                        \
            float vv = acc[mt][r];                                                     \
            EPILOGUE                                                                   \
        }

// QKV: grid (32, 48): y = weight*16 + n-tile. Outputs split hi/lo.
__global__ __launch_bounds__(256) void gemm_qkv_k(
    const bf16* __restrict__ Ah, const bf16* __restrict__ Al,
    const bf16* __restrict__ Bqh, const bf16* __restrict__ Bql,
    const bf16* __restrict__ Bkh, const bf16* __restrict__ Bkl,
    const bf16* __restrict__ Bvh, const bf16* __restrict__ Bvl,
    bf16* Cqh, bf16* Cql, bf16* Ckh, bf16* Ckl, bf16* Cvh, bf16* Cvl) {
    int gy = blockIdx.y, zw = gy >> 4;
    const bf16* Bh = (zw == 0) ? Bqh : (zw == 1) ? Bkh : Bvh;
    const bf16* Bl = (zw == 0) ? Bql : (zw == 1) ? Bkl : Bvl;
    bf16* Ch = (zw == 0) ? Cqh : (zw == 1) ? Ckh : Cvh;
    bf16* Cl = (zw == 0) ? Cql : (zw == 1) ? Ckl : Cvl;
    GEMM64_SPLIT_BODY((gy & 15) * 64, {
        bf16 hi = (bf16)vv;
        Ch[(size_t)gm * D_ + n0 + gnl] = hi;
        Cl[(size_t)gm * D_ + n0 + gnl] = (bf16)(vv - (float)hi);
    })
}

// WO: grid (32, 16): C = X + A@B (direct fp32 store).
__global__ __launch_bounds__(256) void gemm_wo_k(
    const bf16* __restrict__ Ah, const bf16* __restrict__ Al,
    const bf16* __restrict__ Bh, const bf16* __restrict__ Bl,
    float* __restrict__ C, const float* __restrict__ X) {
    GEMM64_SPLIT_BODY(blockIdx.y * 64, {
        C[(size_t)gm * D_ + n0 + gnl] = X[(size_t)gm * D_ + n0 + gnl] + vv;
    })
}

// ---------------------------------------------------------------------------
// Split-bf16 MFMA flash attention. Block = (qt desc, h, b): 64 q-rows, 4 waves.
// ---------------------------------------------------------------------------
#define AP 72

__global__ __launch_bounds__(256) void attn_mfma_k(
    const bf16* __restrict__ qhp, const bf16* __restrict__ qlp,
    const bf16* __restrict__ khp, const bf16* __restrict__ klp,
    const bf16* __restrict__ vhp, const bf16* __restrict__ vlp,
    bf16* __restrict__ aoh, bf16* __restrict__ aol) {
    int qt = (int)gridDim.x - 1 - (int)blockIdx.x;  // deep tiles first
    int h = blockIdx.y, b = blockIdx.z;
    __shared__ bf16 Ksh[64 * AP], Ksl[64 * AP], VTh[64 * AP], VTl[64 * AP];
    __shared__ bf16 Ph[4][16 * AP], Pl[4][16 * AP];
    int t = threadIdx.x, wv = t >> 6, ln = t & 63, l15 = ln & 15, qd = ln >> 4;

    bf16x8 aqh[2], aql[2];
    {
        size_t qb = ((size_t)(b * S_ + qt * 64 + wv * 16 + l15)) * D_ + h * 64 + qd * 8;
        aqh[0] = *(const bf16x8*)(qhp + qb);
        aqh[1] = *(const bf16x8*)(qhp + qb + 32);
        aql[0] = *(const bf16x8*)(qlp + qb);
        aql[1] = *(const bf16x8*)(qlp + qb + 32);
    }
    f32x4 oacc[4];
    float mrow[4], lrow[4];
#pragma unroll
    for (int i = 0; i < 4; i++) {
        oacc[i] = (f32x4){0.f, 0.f, 0.f, 0.f};
        mrow[i] = -1e30f; lrow[i] = 0.0f;
    }

    for (int kt = 0; kt <= qt; kt++) {
        __syncthreads();
#pragma unroll
        for (int j = 0; j < 2; j++) {
            int idx = t + j * 256;
            int row = idx >> 3, ch = (idx & 7) * 8;
            size_t g = ((size_t)(b * S_ + kt * 64 + row)) * D_ + h * 64 + ch;
            *(bf16x8*)&Ksh[row * AP + ch] = *(const bf16x8*)(khp + g);
            *(bf16x8*)&Ksl[row * AP + ch] = *(const bf16x8*)(klp + g);
            bf16x8 vvh = *(const bf16x8*)(vhp + g);
            bf16x8 vvl = *(const bf16x8*)(vlp + g);
#pragma unroll
            for (int jj = 0; jj < 8; jj++) {
                VTh[(ch + jj) * AP + row] = vvh[jj];
                VTl[(ch + jj) * AP + row] = vvl[jj];
            }
        }
        __syncthreads();

        f32x4 sacc[4];
#pragma unroll
        for (int nt = 0; nt < 4; nt++) sacc[nt] = (f32x4){0.f, 0.f, 0.f, 0.f};
#pragma unroll
        for (int ks = 0; ks < 2; ks++) {
#pragma unroll
            for (int nt = 0; nt < 4; nt++) {
                bf16x8 bh = *(const bf16x8*)&Ksh[(nt * 16 + l15) * AP + ks * 32 + qd * 8];
                bf16x8 bl = *(const bf16x8*)&Ksl[(nt * 16 + l15) * AP + ks * 32 + qd * 8];
                sacc[nt] = __builtin_amdgcn_mfma_f32_16x16x32_bf16(aqh[ks], bh, sacc[nt], 0, 0, 0);
                sacc[nt] = __builtin_amdgcn_mfma_f32_16x16x32_bf16(aqh[ks], bl, sacc[nt], 0, 0, 0);
                sacc[nt] = __builtin_amdgcn_mfma_f32_16x16x32_bf16(aql[ks], bh, sacc[nt], 0, 0, 0);
            }
        }
        bool diag = (kt == qt);
#pragma unroll
        for (int r = 0; r < 4; r++) {
            float s0[4];
#pragma unroll
            for (int nt = 0; nt < 4; nt++) {
                s0[nt] = sacc[nt][r] * 0.125f;
                if (diag && (nt * 16 + l15) > (wv * 16 + qd * 4 + r)) s0[nt] = -1e30f;
            }
            float vmax = fmaxf(fmaxf(s0[0], s0[1]), fmaxf(s0[2], s0[3]));
            for (int off = 1; off < 16; off <<= 1) vmax = fmaxf(vmax, __shfl_xor(vmax, off));
            float mnew = fmaxf(mrow[r], vmax);
            float alpha = expf(mrow[r] - mnew);
            float p[4], rs = 0.0f;
#pragma unroll
            for (int nt = 0; nt < 4; nt++) { p[nt] = expf(s0[nt] - mnew); rs += p[nt]; }
            for (int off = 1; off < 16; off <<= 1) rs += __shfl_xor(rs, off);
            lrow[r] = lrow[r] * alpha + rs;
            mrow[r] = mnew;
#pragma unroll
            for (int nt = 0; nt < 4; nt++) oacc[nt][r] *= alpha;
            int prow = qd * 4 + r;
#pragma unroll
            for (int nt = 0; nt < 4; nt++) {
                bf16 hi = (bf16)p[nt];
                Ph[wv][prow * AP + nt * 16 + l15] = hi;
                Pl[wv][prow * AP + nt * 16 + l15] = (bf16)(p[nt] - (float)hi);
            }
        }
        // PV: same-wave LDS RAW (in-order DS pipe), no barrier needed.
#pragma unroll
        for (int ks2 = 0; ks2 < 2; ks2++) {
            bf16x8 aph = *(const bf16x8*)&Ph[wv][l15 * AP + ks2 * 32 + qd * 8];
            bf16x8 apl = *(const bf16x8*)&Pl[wv][l15 * AP + ks2 * 32 + qd * 8];
#pragma unroll
            for (int nt = 0; nt < 4; nt++) {
                bf16x8 bvh = *(const bf16x8*)&VTh[(nt * 16 + l15) * AP + ks2 * 32 + qd * 8];
                bf16x8 bvl = *(const bf16x8*)&VTl[(nt * 16 + l15) * AP + ks2 * 32 + qd * 8];
                oacc[nt] = __builtin_amdgcn_mfma_f32_16x16x32_bf16(aph, bvh, oacc[nt], 0, 0, 0);
                oacc[nt] = __builtin_amdgcn_mfma_f32_16x16x32_bf16(aph, bvl, oacc[nt], 0, 0, 0);
                oacc[nt] = __builtin_amdgcn_mfma_f32_16x16x32_bf16(apl, bvh, oacc[nt], 0, 0, 0);
            }
        }
    }

#pragma unroll
    for (int r = 0; r < 4; r++) {
        float inv = 1.0f / lrow[r];
        size_t rowa = ((size_t)(b * S_ + qt * 64 + wv * 16 + qd * 4 + r)) * D_ + h * 64;
#pragma unroll
        for (int nt = 0; nt < 4; nt++) {
            float o = oacc[nt][r] * inv;
            bf16 hi = (bf16)o;
            aoh[rowa + nt * 16 + l15] = hi;
            aol[rowa + nt * 16 + l15] = (bf16)(o - (float)hi);
        }
    }
}

// ---------------------------------------------------------------------------
// Router: 4 tokens/block (wave each). fp32 logits -> softmax -> top2.
// ---------------------------------------------------------------------------
__global__ __launch_bounds__(256) void router_k(const float* __restrict__ h,
                                                const float* __restrict__ rw,
                                                int* __restrict__ tidx,
                                                float* __restrict__ tgate,
                                                int* __restrict__ ecnt,
                                                float* __restrict__ psum) {
    int wv = threadIdx.x >> 6, ln = threadIdx.x & 63;
    int tok = blockIdx.x * 4 + wv;
    const float* hr = h + (size_t)tok * D_;
    float acc[NE];
#pragma unroll
    for (int e = 0; e < NE; e++) acc[e] = 0.0f;
    int base = ln * 16;
#pragma unroll
    for (int c = 0; c < 4; c++) {
        float4 hv = *(const float4*)(hr + base + c * 4);
        const float* rp = rw + (size_t)(base + c * 4) * NE;
        float hx[4] = {hv.x, hv.y, hv.z, hv.w};
#pragma unroll
        for (int jj = 0; jj < 4; jj++)
#pragma unroll
            for (int e = 0; e < NE; e++)
                acc[e] = fmaf(hx[jj], rp[jj * NE + e], acc[e]);
    }
#pragma unroll
    for (int e = 0; e < NE; e++)
        for (int off = 32; off; off >>= 1) acc[e] += __shfl_down(acc[e], off);

    __shared__ float pb[4][NE];
    if (ln == 0) {
        float mx = acc[0];
#pragma unroll
        for (int e = 1; e < NE; e++) mx = fmaxf(mx, acc[e]);
        float p[NE], ssum = 0.0f;
#pragma unroll
        for (int e = 0; e < NE; e++) { p[e] = expf(acc[e] - mx); ssum += p[e]; }
        float inv = 1.0f / ssum;
#pragma unroll
        for (int e = 0; e < NE; e++) p[e] *= inv;
        int i0 = 0; float b0 = p[0];
#pragma unroll
        for (int e = 1; e < NE; e++) if (p[e] > b0) { b0 = p[e]; i0 = e; }
        int i1 = -1; float b1v = -1.0f;
#pragma unroll
        for (int e = 0; e < NE; e++) if (e != i0 && p[e] > b1v) { b1v = p[e]; i1 = e; }
        tidx[tok * 2] = i0; tidx[tok * 2 + 1] = i1;
        tgate[tok * 2] = b0; tgate[tok * 2 + 1] = b1v;
        atomicAdd(&ecnt[i0], 1);
        atomicAdd(&ecnt[i1], 1);
#pragma unroll
        for (int e = 0; e < NE; e++) pb[wv][e] = p[e];
    }
    __syncthreads();
    if (threadIdx.x < NE) {
        float s2 = pb[0][threadIdx.x] + pb[1][threadIdx.x] + pb[2][threadIdx.x] + pb[3][threadIdx.x];
        atomicAdd(&psum[threadIdx.x], s2);
    }
}

__global__ void passb_k(const int* __restrict__ ecnt, const float* __restrict__ psum,
                        int* __restrict__ eoffp, int* __restrict__ ecnt2,
                        float* __restrict__ out_tail) {
    if (threadIdx.x == 0) {
        int off = 0; float loss = 0.0f;
        for (int e = 0; e < NE; e++) {
            eoffp[e] = off;
            int c = ecnt[e];
            off += (c + 127) & ~127;
            loss += (c * (1.0f / 4096.0f)) * (psum[e] * (1.0f / 2048.0f));
            out_tail[1 + e] = (float)c;
            ecnt2[e] = 0;
        }
        eoffp[NE] = off;
        out_tail[0] = 8.0f * loss;
    }
}

// scatter: slot list per expert + inverse map (slot of each (tok,k)).
__global__ __launch_bounds__(256) void scatter_k(const int* __restrict__ tidx,
                                                 const int* __restrict__ eoffp,
                                                 int* __restrict__ ecnt2,
                                                 int* __restrict__ stok,
                                                 int* __restrict__ sidx) {
    int tok = blockIdx.x * 256 + threadIdx.x;
    for (int k = 0; k < 2; k++) {
        int e = tidx[tok * 2 + k];
        int pos = eoffp[e] + atomicAdd(&ecnt2[e], 1);
        stok[pos] = tok;
        sidx[tok * 2 + k] = pos;
    }
}

// ---------------------------------------------------------------------------
// MoE GEMM1 (plain bf16): 128x128 tile, BK=32, 4 waves 2x2. act = gelu(h@w1+b1)
// ---------------------------------------------------------------------------
#define MLD 40

__global__ __launch_bounds__(256) void moe_gemm1_k(const bf16* __restrict__ hB,
                                                   const bf16* __restrict__ w1t,
                                                   const float* __restrict__ b1,
                                                   const int* __restrict__ eoffp,
                                                   const int* __restrict__ stok,
                                                   bf16* __restrict__ act) {
    int m0 = blockIdx.x * 128, n0 = blockIdx.y * 128;
    if (m0 >= eoffp[NE]) return;
    int e = 0;
#pragma unroll
    for (int i = 1; i < NE; i++) if (m0 >= eoffp[i]) e = i;

    __shared__ bf16 As[128 * MLD];
    __shared__ bf16 Bs[128 * MLD];
    __shared__ int tok_l[128];
    int t = threadIdx.x;
    if (t < 128) tok_l[t] = stok[m0 + t];

    int wv = t >> 6, ln = t & 63;
    int wm = wv >> 1, wn = wv & 1;
    int lane15 = ln & 15, quad = ln >> 4;
    f32x4 acc[4][4];
#pragma unroll
    for (int mt = 0; mt < 4; mt++)
#pragma unroll
        for (int nt = 0; nt < 4; nt++) acc[mt][nt] = (f32x4){0.f, 0.f, 0.f, 0.f};

    const bf16* Bbase = w1t + ((size_t)e * FF_ + n0) * D_;

    for (int k0 = 0; k0 < D_; k0 += 32) {
        __syncthreads();
#pragma unroll
        for (int j = 0; j < 2; j++) {
            int idx = t + j * 256;
            int row = idx >> 2, kc = (idx & 3) * 8;
            uint4 av = *(const uint4*)(hB + (size_t)tok_l[row] * D_ + k0 + kc);
            *(uint4*)&As[row * MLD + kc] = av;
            uint4 bv = *(const uint4*)(Bbase + (size_t)row * D_ + k0 + kc);
            *(uint4*)&Bs[row * MLD + kc] = bv;
        }
        __syncthreads();
        bf16x8 af[4], bfr[4];
#pragma unroll
        for (int mt = 0; mt < 4; mt++)
            af[mt] = *(const bf16x8*)&As[(wm * 64 + mt * 16 + lane15) * MLD + quad * 8];
#pragma unroll
        for (int nt = 0; nt < 4; nt++)
            bfr[nt] = *(const bf16x8*)&Bs[(wn * 64 + nt * 16 + lane15) * MLD + quad * 8];
#pragma unroll
        for (int mt = 0; mt < 4; mt++)
#pragma unroll
            for (int nt = 0; nt < 4; nt++)
                acc[mt][nt] = __builtin_amdgcn_mfma_f32_16x16x32_bf16(af[mt], bfr[nt], acc[mt][nt], 0, 0, 0);
    }

    const float* b1e = b1 + (size_t)e * FF_;
#pragma unroll
    for (int mt = 0; mt < 4; mt++)
#pragma unroll
        for (int nt = 0; nt < 4; nt++) {
            int gn = n0 + wn * 64 + nt * 16 + lane15;
            float bias = b1e[gn];
#pragma unroll
            for (int r = 0; r < 4; r++) {
                int gm = m0 + wm * 64 + mt * 16 + quad * 4 + r;
                float vv = acc[mt][nt][r] + bias;
                act[(size_t)gm * FF_ + gn] = (bf16)gelu_f(vv);
            }
        }
}

// ---------------------------------------------------------------------------
// MoE GEMM2 (plain bf16): 64x64 tile, BK=32, K=4096, plain fp32 stores to y.
// Grid (80, 16). y[slot][D] = act[slot]@w2[e] + b2[e].
// ---------------------------------------------------------------------------
__global__ __launch_bounds__(256) void moe_gemm2_k(const bf16* __restrict__ act,
                                                   const bf16* __restrict__ w2t,
                                                   const float* __restrict__ b2,
                                                   const int* __restrict__ eoffp,
                                                   float* __restrict__ y) {
    int m0 = blockIdx.x * 64;
    if (m0 >= eoffp[NE]) return;
    int e = 0;
#pragma unroll
    for (int i = 1; i < NE; i++) if (m0 >= eoffp[i]) e = i;
    int n0 = blockIdx.y * 64;

    __shared__ bf16 As[64 * MLD];
    __shared__ bf16 Bs[64 * MLD];
    int t = threadIdx.x;
    int wv = t >> 6, ln = t & 63, l15 = ln & 15, qd = ln >> 4;
    int srow = t >> 2, skc = (t & 3) * 8;

    f32x4 acc[4];
#pragma unroll
    for (int mt = 0; mt < 4; mt++) acc[mt] = (f32x4){0.f, 0.f, 0.f, 0.f};

    const bf16* Bbase = w2t + ((size_t)e * D_ + n0) * FF_;

    for (int k0 = 0; k0 < FF_; k0 += 32) {
        __syncthreads();
        *(bf16x8*)&As[srow * MLD + skc] = *(const bf16x8*)(act + (size_t)(m0 + srow) * FF_ + k0 + skc);
        *(bf16x8*)&Bs[srow * MLD + skc] = *(const bf16x8*)(Bbase + (size_t)srow * FF_ + k0 + skc);
        __syncthreads();
        bf16x8 af[4];
#pragma unroll
        for (int mt = 0; mt < 4; mt++)
            af[mt] = *(const bf16x8*)&As[(mt * 16 + l15) * MLD + qd * 8];
        bf16x8 bfr = *(const bf16x8*)&Bs[(wv * 16 + l15) * MLD + qd * 8];
#pragma unroll
        for (int mt = 0; mt < 4; mt++)
            acc[mt] = __builtin_amdgcn_mfma_f32_16x16x32_bf16(af[mt], bfr, acc[mt], 0, 0, 0);
    }

    int gn = n0 + wv * 16 + l15;
    float bias = b2[(size_t)e * D_ + gn];
#pragma unroll
    for (int mt = 0; mt < 4; mt++)
#pragma unroll
        for (int r = 0; r < 4; r++) {
            int gm = m0 + mt * 16 + qd * 4 + r;
            y[(size_t)gm * D_ + gn] = acc[mt][r] + bias;
        }
}

// combine: out[tok] += g0*y[s0] + g1*y[s1]. One block per token.
__global__ __launch_bounds__(256) void combine_k(const float* __restrict__ y,
                                                 const int* __restrict__ sidx,
                                                 const float* __restrict__ tgate,
                                                 float* __restrict__ out) {
    int tok = blockIdx.x;
    int d = threadIdx.x * 4;
    int s0 = sidx[tok * 2], s1 = sidx[tok * 2 + 1];
    float g0 = tgate[tok * 2], g1 = tgate[tok * 2 + 1];
    float4 a = *(const float4*)(y + (size_t)s0 * D_ + d);
    float4 b = *(const float4*)(y + (size_t)s1 * D_ + d);
    float4 o = *(const float4*)(out + (size_t)tok * D_ + d);
    o.x += g0 * a.x + g1 * b.x;
    o.y += g0 * a.y + g1 * b.y;
    o.z += g0 * a.z + g1 * b.z;
    o.w += g0 * a.w + g1 * b.w;
    *(float4*)(out + (size_t)tok * D_ + d) = o;
}

// ---------------------------------------------------------------------------
extern "C" void kernel_launch(void* const* d_in, const int* in_sizes, int n_in,
                              void* d_out, int out_size, void* d_ws, size_t ws_size,
                              hipStream_t stream) {
    const float* x   = (const float*)d_in[0];
    const float* anw = (const float*)d_in[1];
    const float* wq  = (const float*)d_in[2];
    const float* wk  = (const float*)d_in[3];
    const float* wv  = (const float*)d_in[4];
    const float* wo  = (const float*)d_in[5];
    const float* mnw = (const float*)d_in[6];
    const float* rw  = (const float*)d_in[7];
    const float* w1  = (const float*)d_in[8];
    const float* b1  = (const float*)d_in[9];
    const float* w2  = (const float*)d_in[10];
    const float* b2  = (const float*)d_in[11];
    float* out = (float*)d_out;

    char* p = (char*)d_ws;
    auto take = [&](size_t n) { char* r = p; p += (n + 255) & ~(size_t)255; return r; };
    bf16* h1h = (bf16*)take((size_t)OUTN * 2);
    bf16* h1l = (bf16*)take((size_t)OUTN * 2);
    bf16* qh  = (bf16*)take((size_t)OUTN * 2);
    bf16* ql  = (bf16*)take((size_t)OUTN * 2);
    bf16* kh  = (bf16*)take((size_t)OUTN * 2);
    bf16* kl  = (bf16*)take((size_t)OUTN * 2);
    bf16* vh  = (bf16*)take((size_t)OUTN * 2);
    bf16* vl  = (bf16*)take((size_t)OUTN * 2);
    bf16* wqth = (bf16*)take((size_t)D_ * D_ * 2);
    bf16* wqtl = (bf16*)take((size_t)D_ * D_ * 2);
    bf16* wkth = (bf16*)take((size_t)D_ * D_ * 2);
    bf16* wktl = (bf16*)take((size_t)D_ * D_ * 2);
    bf16* wvth = (bf16*)take((size_t)D_ * D_ * 2);
    bf16* wvtl = (bf16*)take((size_t)D_ * D_ * 2);
    bf16* woth = (bf16*)take((size_t)D_ * D_ * 2);
    bf16* wotl = (bf16*)take((size_t)D_ * D_ * 2);
    bf16* w1t = (bf16*)take((size_t)NE * FF_ * D_ * 2);
    bf16* w2t = (bf16*)take((size_t)NE * FF_ * D_ * 2);
    bf16* act = (bf16*)take((size_t)CAP * FF_ * 2);
    int*   tidx  = (int*)take(NTOK * 2 * 4);
    float* tgate = (float*)take(NTOK * 2 * 4);
    int*   sidx  = (int*)take(NTOK * 2 * 4);
    int*   ecnt  = (int*)take(64);
    int*   ecnt2 = (int*)take(64);
    float* psum  = (float*)take(64);
    int*   eoffp = (int*)take(64);
    int*   stok  = (int*)take(CAP * 4);

    // aliases over dead buffers:
    bf16*  aoh = h1h;            // h1 dead after QKV gemm
    bf16*  aol = h1l;
    float* h_f = (float*)qh;     // q dead after attention (spans qh+ql, 8 MB)
    bf16*  h_b = kh;             // k dead after attention
    float* y   = (float*)vh;     // v + attn weight splits dead after WO: 8+16=24 MB >= CAP*D*4=21 MB

    hipMemsetAsync(ecnt, 0, NE * 4, stream);
    hipMemsetAsync(psum, 0, NE * 4, stream);
    hipMemsetAsync(stok, 0, CAP * 4, stream);

    // weight transposes
    trans_split_k<<<dim3(32, 32, 4), 256, 0, stream>>>(wq, wk, wv, wo,
        wqth, wqtl, wkth, wktl, wvth, wvtl, woth, wotl);
    transpose_cast_k<<<dim3(FF_ / 32, D_ / 32, NE), 256, 0, stream>>>(w1, w1t, D_, FF_);
    transpose_cast_k<<<dim3(D_ / 32, FF_ / 32, NE), 256, 0, stream>>>(w2, w2t, FF_, D_);

    // attention path (split-bf16 MFMA, fp32 fidelity for router)
    rmsnorm_k<<<NTOK, 256, 0, stream>>>(x, anw, nullptr, h1h, h1l);
    gemm_qkv_k<<<dim3(32, 48), 256, 0, stream>>>(h1h, h1l,
        wqth, wqtl, wkth, wktl, wvth, wvtl, qh, ql, kh, kl, vh, vl);
    attn_mfma_k<<<dim3(16, 16, 2), 256, 0, stream>>>(qh, ql, kh, kl, vh, vl, aoh, aol);
    gemm_wo_k<<<dim3(32, 16), 256, 0, stream>>>(aoh, aol, woth, wotl, out, x);

    // MoE
    rmsnorm_k<<<NTOK, 256, 0, stream>>>(out, mnw, h_f, h_b, nullptr);
    router_k<<<NTOK / 4, 256, 0, stream>>>(h_f, rw, tidx, tgate, ecnt, psum);
    passb_k<<<1, 64, 0, stream>>>(ecnt, psum, eoffp, ecnt2, out + OUTN);
    scatter_k<<<NTOK / 256, 256, 0, stream>>>(tidx, eoffp, ecnt2, stok, sidx);
    moe_gemm1_k<<<dim3(CAP / 128, FF_ / 128), 256, 0, stream>>>(h_b, w1t, b1, eoffp, stok, act);
    moe_gemm2_k<<<dim3(CAP / 64, D_ / 64), 256, 0, stream>>>(act, w2t, b2, eoffp, y);
    combine_k<<<NTOK, 256, 0, stream>>>(y, sidx, tgate, out);
}